// Round 4
// baseline (786.225 us; speedup 1.0000x reference)
//
#include <hip/hip_runtime.h>
#include <hip/hip_bf16.h>

typedef __attribute__((ext_vector_type(4))) float f32x4;
typedef __attribute__((ext_vector_type(8))) short short8;
typedef __attribute__((ext_vector_type(4))) short short4_t;

#define LTOK 64
#define CDIM 256

static __device__ __forceinline__ short f2bf(float f) {
    __hip_bfloat16 h = __float2bfloat16(f);
    union { __hip_bfloat16 b; short s; } u; u.b = h;
    return u.s;
}

// ---------------- prep kernels ----------------
// Weights pre-swizzled into MFMA B-fragment order (one coalesced 1KB wave load per fragment).
__global__ void prep_weights(const float* __restrict__ qw, const float* __restrict__ pw,
                             short* __restrict__ wqs, short* __restrict__ wps) {
    int i = blockIdx.x * 256 + threadIdx.x;     // grid 768*256 = 196608
    if (i < 768 * 256) {
        int row = i >> 8, col = i & 255;
        int nt = row >> 4, lcr = row & 15;
        int kt = col >> 5, lg = (col >> 3) & 3, j = col & 7;
        wqs[(size_t)(((nt * 8 + kt) * 64) + lg * 16 + lcr) * 8 + j] = f2bf(qw[i]);
    }
    if (i < 256 * 256) {
        int row = i >> 8, col = i & 255;
        int gs = row >> 4, lcr = row & 15;          // global 16-col strip 0..15
        int h = col >> 5, lg = (col >> 3) & 3, j = col & 7;
        wps[(size_t)(((gs * 8 + h) * 64) + lg * 16 + lcr) * 8 + j] = f2bf(pw[i]);
    }
}

__global__ void prep_bias(const float* __restrict__ w1, const float* __restrict__ b1,
                          const float* __restrict__ w2, const float* __restrict__ b2,
                          const float* __restrict__ lsc, float* __restrict__ biasT,
                          float* __restrict__ scT) {
    int t = threadIdx.x;                         // 1 block, 128 threads
    if (t < 8) scT[t] = expf(fminf(lsc[t], logf(100.0f)));
    if (t < 127) {
        float delta = (float)(t - 63);
        float sg = (delta > 0.f) ? 1.f : ((delta < 0.f) ? -1.f : 0.f);
        float r = sg * log1pf(fabsf(delta));
        float acc[8];
        #pragma unroll
        for (int q = 0; q < 8; ++q) acc[q] = b2[q];
        for (int m = 0; m < 384; ++m) {
            float hid = fmaxf(fmaf(r, w1[m * 2 + 1], b1[m]), 0.f);
            #pragma unroll
            for (int q = 0; q < 8; ++q) acc[q] = fmaf(hid, w2[q * 384 + m], acc[q]);
        }
        #pragma unroll
        for (int q = 0; q < 8; ++q) biasT[q * 127 + t] = acc[q];
    }
}

// ---------------- main fused kernel ----------------
// 512 threads (8 waves) per window. X staged half-K at a time in fragment
// layout (conflict-free). qkv: wave w -> strips 3(w&3)..+2, m-tiles 2(w>>2)..+1.
// attention: waves 0-3 head 2g, waves 4-7 head 2g+1. proj: wave w -> cols 32w..+31.
// LDS = 74752 B -> 2 blocks/CU -> 16 waves/CU. VGPR capped at 128 by launch_bounds.

__global__ void __launch_bounds__(512, 4)
fused_win_attn(const float* __restrict__ x,
               const float* __restrict__ qkv_b,
               const float* __restrict__ proj_b,
               const short* __restrict__ wqs,
               const short* __restrict__ wps,
               const float* __restrict__ biasT,
               const float* __restrict__ scT,
               float* __restrict__ out)
{
    __shared__ short XSF[16 * 64 * 8];     // x fragments, half-K, linear  16384 B
    __shared__ short QG[64 * 72];          // q pair [token][d0..63]        9216 B
    __shared__ short KG[64 * 72];          //                               9216 B
    __shared__ short VT[64 * 72];          // v pair transposed [d][token]  9216 B
    __shared__ short PBs[2][64 * 72];      // P per head                   18432 B
    __shared__ short AOs[2][64 * 40];      // attn out per head            10240 B
    __shared__ float NSQ[512];             // sumsq partials                2048 B

    const int tid = threadIdx.x;
    const int w  = tid >> 6;
    const int l  = tid & 63;
    const int lg = l >> 4;
    const int lc = l & 15;
    const int blk = blockIdx.x;

    const float* xb = x + (size_t)blk * (LTOK * CDIM);

    // qkv roles
    const int sb  = (w & 3) * 3;           // strip base (3 strips per wave)
    const int mtb = (w >> 2) * 2;          // m-tile base (2 per wave)
    // attention roles
    const int hh  = w >> 2;                // head within pair
    const int mw  = w & 3;                 // m-tile in attention

    // staging roles: wave stages frags fA = w, fB = 8+w
    const int mtA = w & 3,        kA = w >> 2;
    const int mtB = (8 + w) & 3,  kB = (8 + w) >> 2;
    const float* gA = xb + (size_t)(mtA * 16 + lc) * CDIM + lg * 8;
    const float* gB = xb + (size_t)(mtB * 16 + lc) * CDIM + lg * 8;
    short* sA = XSF + (size_t)(w * 64 + l) * 8;
    short* sB = XSF + (size_t)((8 + w) * 64 + l) * 8;

    f32x4 accP[4][2];
    #pragma unroll
    for (int a = 0; a < 4; ++a) { accP[a][0] = (f32x4){0,0,0,0}; accP[a][1] = (f32x4){0,0,0,0}; }
    const f32x4 fzero = {0.f, 0.f, 0.f, 0.f};

    #pragma unroll 1
    for (int g = 0; g < 4; ++g) {
        f32x4 acc[3][2];
        #pragma unroll
        for (int t = 0; t < 3; ++t) { acc[t][0] = fzero; acc[t][1] = fzero; }

        #pragma unroll 1
        for (int ht = 0; ht < 2; ++ht) {
            // ---- stage half ht: 16 fragments, linear writes (conflict-free) ----
            {
                f32x4 a0 = *(const f32x4*)(gA + (ht * 4 + kA) * 32);
                f32x4 a1 = *(const f32x4*)(gA + (ht * 4 + kA) * 32 + 4);
                f32x4 b0 = *(const f32x4*)(gB + (ht * 4 + kB) * 32);
                f32x4 b1 = *(const f32x4*)(gB + (ht * 4 + kB) * 32 + 4);
                short8 ta, tb;
                ta[0]=f2bf(a0[0]); ta[1]=f2bf(a0[1]); ta[2]=f2bf(a0[2]); ta[3]=f2bf(a0[3]);
                ta[4]=f2bf(a1[0]); ta[5]=f2bf(a1[1]); ta[6]=f2bf(a1[2]); ta[7]=f2bf(a1[3]);
                tb[0]=f2bf(b0[0]); tb[1]=f2bf(b0[1]); tb[2]=f2bf(b0[2]); tb[3]=f2bf(b0[3]);
                tb[4]=f2bf(b1[0]); tb[5]=f2bf(b1[1]); tb[6]=f2bf(b1[2]); tb[7]=f2bf(b1[3]);
                *(short8*)sA = ta;
                *(short8*)sB = tb;
            }
            __syncthreads();                               // staged & XSF free from prev use
            // ---- compute half: 3 strips x 2 m-tiles, 4 kt ----
            #pragma unroll
            for (int ktL = 0; ktL < 4; ++ktL) {
                short8 Af0 = *(const short8*)(XSF + (size_t)((ktL * 4 + mtb) * 64 + l) * 8);
                short8 Af1 = *(const short8*)(XSF + (size_t)((ktL * 4 + mtb + 1) * 64 + l) * 8);
                #pragma unroll
                for (int tt = 0; tt < 3; ++tt) {
                    const int strip = sb + tt;
                    const int gnt = (strip >> 2) * 16 + g * 4 + (strip & 3);
                    short8 Bf = *(const short8*)(wqs + (size_t)((gnt * 8 + ht * 4 + ktL) * 64 + l) * 8);
                    acc[tt][0] = __builtin_amdgcn_mfma_f32_16x16x32_bf16(Af0, Bf, acc[tt][0], 0, 0, 0);
                    acc[tt][1] = __builtin_amdgcn_mfma_f32_16x16x32_bf16(Af1, Bf, acc[tt][1], 0, 0, 0);
                }
            }
            __syncthreads();                               // compute done (WAR before restage / B1)
        }

        // ---- qkv epilogue: write QG/KG/VT + NSQ ----
        #pragma unroll
        for (int tt = 0; tt < 3; ++tt) {
            const int strip = sb + tt;
            const int s = strip >> 2, nt = strip & 3;
            const float bq = qkv_b[s * 256 + g * 64 + nt * 16 + lc];
            #pragma unroll
            for (int m = 0; m < 2; ++m) {
                const int mt = mtb + m;
                if (s == 2) {
                    short4_t pk;
                    #pragma unroll
                    for (int i = 0; i < 4; ++i) pk[i] = f2bf(acc[tt][m][i] + bq);
                    *(short4_t*)(VT + (nt * 16 + lc) * 72 + mt * 16 + lg * 4) = pk;
                } else {
                    short* dst = s ? KG : QG;
                    #pragma unroll
                    for (int i = 0; i < 4; ++i) {
                        float v = acc[tt][m][i] + bq;
                        dst[(mt * 16 + lg * 4 + i) * 72 + nt * 16 + lc] = f2bf(v);
                        float t2 = v * v;
                        t2 += __shfl_xor(t2, 1);
                        t2 += __shfl_xor(t2, 2);
                        t2 += __shfl_xor(t2, 4);
                        t2 += __shfl_xor(t2, 8);
                        if (lc == 0) NSQ[s * 256 + (mt * 16 + lg * 4 + i) * 4 + nt] = t2;
                    }
                }
            }
        }
        __syncthreads();                                   // B1: q,k,v + NSQ ready

        // ---- QK^T + softmax (wave group = head) ----
        {
            const int h = 2 * g + hh;
            const float sc = scT[h];
            short8 Aq = *(const short8*)(QG + (mw * 16 + lc) * 72 + hh * 32 + lg * 8);
            f32x4 pacc[4];
            #pragma unroll
            for (int nt = 0; nt < 4; ++nt) {
                short8 Bk = *(const short8*)(KG + (nt * 16 + lc) * 72 + hh * 32 + lg * 8);
                pacc[nt] = __builtin_amdgcn_mfma_f32_16x16x32_bf16(Aq, Bk, fzero, 0, 0, 0);
            }
            float invq[4], invk[4];
            #pragma unroll
            for (int i = 0; i < 4; ++i) {
                int r = mw * 16 + lg * 4 + i;
                invq[i] = rsqrtf(NSQ[r * 4 + 2 * hh] + NSQ[r * 4 + 2 * hh + 1] + 1e-24f) * sc;
            }
            #pragma unroll
            for (int nt = 0; nt < 4; ++nt) {
                int rk = nt * 16 + lc;
                invk[nt] = rsqrtf(NSQ[256 + rk * 4 + 2 * hh] + NSQ[256 + rk * 4 + 2 * hh + 1] + 1e-24f);
            }
            float p[4][4];
            #pragma unroll
            for (int i = 0; i < 4; ++i) {
                int r = mw * 16 + lg * 4 + i;
                #pragma unroll
                for (int nt = 0; nt < 4; ++nt) {
                    int c = nt * 16 + lc;
                    p[i][nt] = pacc[nt][i] * invq[i] * invk[nt] + biasT[h * 127 + r - c + 63];
                }
            }
            #pragma unroll
            for (int i = 0; i < 4; ++i) {
                float m = fmaxf(fmaxf(p[i][0], p[i][1]), fmaxf(p[i][2], p[i][3]));
                m = fmaxf(m, __shfl_xor(m, 1));
                m = fmaxf(m, __shfl_xor(m, 2));
                m = fmaxf(m, __shfl_xor(m, 4));
                m = fmaxf(m, __shfl_xor(m, 8));
                float ssum = 0.f;
                #pragma unroll
                for (int nt = 0; nt < 4; ++nt) { p[i][nt] = __expf(p[i][nt] - m); ssum += p[i][nt]; }
                ssum += __shfl_xor(ssum, 1);
                ssum += __shfl_xor(ssum, 2);
                ssum += __shfl_xor(ssum, 4);
                ssum += __shfl_xor(ssum, 8);
                float rinv = 1.f / ssum;
                #pragma unroll
                for (int nt = 0; nt < 4; ++nt)
                    PBs[hh][(mw * 16 + lg * 4 + i) * 72 + nt * 16 + lc] = f2bf(p[i][nt] * rinv);
            }
        }
        __syncthreads();                                   // B2: P ready

        // ---- P @ V (wave group = head) ----
        {
            f32x4 oacc[2];
            oacc[0] = fzero; oacc[1] = fzero;
            #pragma unroll
            for (int kt = 0; kt < 2; ++kt) {
                short8 Ap = *(const short8*)(PBs[hh] + (mw * 16 + lc) * 72 + kt * 32 + lg * 8);
                #pragma unroll
                for (int nt2 = 0; nt2 < 2; ++nt2) {
                    short8 Bv = *(const short8*)(VT + (hh * 32 + nt2 * 16 + lc) * 72 + kt * 32 + lg * 8);
                    oacc[nt2] = __builtin_amdgcn_mfma_f32_16x16x32_bf16(Ap, Bv, oacc[nt2], 0, 0, 0);
                }
            }
            #pragma unroll
            for (int nt2 = 0; nt2 < 2; ++nt2)
                #pragma unroll
                for (int i = 0; i < 4; ++i)
                    AOs[hh][(mw * 16 + lg * 4 + i) * 40 + nt2 * 16 + lc] = f2bf(oacc[nt2][i]);
        }
        __syncthreads();                                   // B3: AO ready

        // ---- proj accumulate: wave w owns cols 32w..32w+31 ----
        #pragma unroll
        for (int hh2 = 0; hh2 < 2; ++hh2) {
            const int h2 = 2 * g + hh2;
            short8 Bp0 = *(const short8*)(wps + (size_t)((((w * 2 + 0) * 8 + h2) * 64) + l) * 8);
            short8 Bp1 = *(const short8*)(wps + (size_t)((((w * 2 + 1) * 8 + h2) * 64) + l) * 8);
            #pragma unroll
            for (int mt = 0; mt < 4; ++mt) {
                short8 Aa = *(const short8*)(AOs[hh2] + (mt * 16 + lc) * 40 + lg * 8);
                accP[mt][0] = __builtin_amdgcn_mfma_f32_16x16x32_bf16(Aa, Bp0, accP[mt][0], 0, 0, 0);
                accP[mt][1] = __builtin_amdgcn_mfma_f32_16x16x32_bf16(Aa, Bp1, accP[mt][1], 0, 0, 0);
            }
        }
        // next g's staging (writes XSF) is safe: XSF last read before this g's B1.
    }

    // ---- epilogue: out = accP + proj_b ----
    {
        float* ob = out + (size_t)blk * (LTOK * CDIM);
        float pb0 = proj_b[w * 32 + lc];
        float pb1 = proj_b[w * 32 + 16 + lc];
        #pragma unroll
        for (int mt = 0; mt < 4; ++mt)
            #pragma unroll
            for (int i = 0; i < 4; ++i) {
                ob[(size_t)(mt * 16 + lg * 4 + i) * 256 + w * 32 + lc]      = accP[mt][0][i] + pb0;
                ob[(size_t)(mt * 16 + lg * 4 + i) * 256 + w * 32 + 16 + lc] = accP[mt][1][i] + pb1;
            }
    }
}

extern "C" void kernel_launch(void* const* d_in, const int* in_sizes, int n_in,
                              void* d_out, int out_size, void* d_ws, size_t ws_size,
                              hipStream_t stream) {
    const float* x     = (const float*)d_in[0];
    const float* qkvw  = (const float*)d_in[1];
    const float* qkvb  = (const float*)d_in[2];
    const float* projw = (const float*)d_in[3];
    const float* projb = (const float*)d_in[4];
    const float* lsc   = (const float*)d_in[5];
    const float* w1    = (const float*)d_in[6];
    const float* b1    = (const float*)d_in[7];
    const float* w2    = (const float*)d_in[8];
    const float* b2    = (const float*)d_in[9];
    float* out = (float*)d_out;

    // workspace layout
    short* wqs   = (short*)d_ws;                          // 393216 B
    short* wps   = (short*)((char*)d_ws + 393216);        // 131072 B
    float* biasT = (float*)((char*)d_ws + 524288);        // 4096 B
    float* scT   = (float*)((char*)d_ws + 528384);        // 32 B

    const int nwin = in_sizes[0] / (LTOK * CDIM);         // 4096

    prep_weights<<<768, 256, 0, stream>>>(qkvw, projw, wqs, wps);
    prep_bias<<<1, 128, 0, stream>>>(w1, b1, w2, b2, lsc, biasT, scT);
    fused_win_attn<<<nwin, 512, 0, stream>>>(x, qkvb, projb, wqs, wps, biasT, scT, out);
}

// Round 5
// 773.211 us; speedup vs baseline: 1.0168x; 1.0168x over previous
//
#include <hip/hip_runtime.h>
#include <hip/hip_bf16.h>

typedef __attribute__((ext_vector_type(4))) float f32x4;
typedef __attribute__((ext_vector_type(8))) short short8;

#define LTOK 64
#define CDIM 256

static __device__ __forceinline__ short f2bf(float f) {
    __hip_bfloat16 h = __float2bfloat16(f);
    union { __hip_bfloat16 b; short s; } u; u.b = h;
    return u.s;
}

// ---------------- prep kernels ----------------
// Weights pre-swizzled into MFMA B-fragment order (one coalesced 1KB wave load per fragment).
__global__ void prep_weights(const float* __restrict__ qw, const float* __restrict__ pw,
                             short* __restrict__ wqs, short* __restrict__ wps) {
    int i = blockIdx.x * 256 + threadIdx.x;     // grid 768*256 = 196608
    if (i < 768 * 256) {
        int row = i >> 8, col = i & 255;
        int nt = row >> 4, lcr = row & 15;
        int kt = col >> 5, lg = (col >> 3) & 3, j = col & 7;
        wqs[(size_t)(((nt * 8 + kt) * 64) + lg * 16 + lcr) * 8 + j] = f2bf(qw[i]);
    }
    if (i < 256 * 256) {
        int row = i >> 8, col = i & 255;
        int gs = row >> 4, lcr = row & 15;          // global 16-col strip 0..15
        int h = col >> 5, lg = (col >> 3) & 3, j = col & 7;
        wps[(size_t)(((gs * 8 + h) * 64) + lg * 16 + lcr) * 8 + j] = f2bf(pw[i]);
    }
}

__global__ void prep_bias(const float* __restrict__ w1, const float* __restrict__ b1,
                          const float* __restrict__ w2, const float* __restrict__ b2,
                          const float* __restrict__ lsc, float* __restrict__ biasT,
                          float* __restrict__ scT) {
    int t = threadIdx.x;                         // 1 block, 128 threads
    if (t < 8) scT[t] = expf(fminf(lsc[t], logf(100.0f)));
    if (t < 127) {
        float delta = (float)(t - 63);
        float sg = (delta > 0.f) ? 1.f : ((delta < 0.f) ? -1.f : 0.f);
        float r = sg * log1pf(fabsf(delta));
        float acc[8];
        #pragma unroll
        for (int q = 0; q < 8; ++q) acc[q] = b2[q];
        for (int m = 0; m < 384; ++m) {
            float hid = fmaxf(fmaf(r, w1[m * 2 + 1], b1[m]), 0.f);
            #pragma unroll
            for (int q = 0; q < 8; ++q) acc[q] = fmaf(hid, w2[q * 384 + m], acc[q]);
        }
        #pragma unroll
        for (int q = 0; q < 8; ++q) biasT[q * 127 + t] = acc[q];
    }
}

// ---------------- main fused kernel ----------------
// 512 threads (8 waves) per window. All LDS matrices in MFMA-fragment-linear
// layout: FRAG(buf, rt, kt) at ((kt*4 + rt)*64 + lane)*8 shorts -> every
// operand read is one conflict-free ds_read_b128.
// X staged ONCE (32KB). qkv: wave w -> strips 3(w&3)..+2, m-tiles 2(w>>2)..+1.
// attention: waves 0-3 = head 2g, waves 4-7 = head 2g+1 (concurrent).
// P is wave-private (QK^T rows mw consumed by same wave in PV) -> no barrier.
// AOF shares the QGF buffer (slot (hh,mw) read as Aq before written as AO by
// the same wave). proj: wave w owns output cols 32w..32w+31.
// 3 barriers per g. LDS = 79872 B -> 2 blocks/CU -> 16 waves/CU.
// __launch_bounds__(512,2): empirically caps VGPR at 128 (R4: (512,4) -> 64).

__global__ void __launch_bounds__(512, 2)
fused_win_attn(const float* __restrict__ x,
               const float* __restrict__ qkv_b,
               const float* __restrict__ proj_b,
               const short* __restrict__ wqs,
               const short* __restrict__ wps,
               const float* __restrict__ biasT,
               const float* __restrict__ scT,
               float* __restrict__ out)
{
    __shared__ short XSF[16384];     // x frags [kt 0..7][rt 0..3]          32768 B
    __shared__ short U[4096];        // QGF [kt 0..1][rt 0..3] / AOF         8192 B
    __shared__ short KGF[4096];      // k frags [kt 0..1][rt 0..3]           8192 B
    __shared__ short VTF[4096];      // v^T frags [kt_tok 0..1][rt_d 0..3]   8192 B
    __shared__ short PBF[8192];      // P, wave-private 1024-short slices   16384 B
    __shared__ float NSQ[512];       // sumsq partials [s][row][nt]          2048 B
    __shared__ float BT[1024];       // bias table [h][rel+63]               4096 B

    const int tid = threadIdx.x;
    const int w  = tid >> 6;
    const int l  = tid & 63;
    const int lg = l >> 4;
    const int lc = l & 15;
    const int blk = blockIdx.x;
    const int li4 = lg * 4;                    // row offset of acc element i=0

    // ---- stage bias table ----
    #pragma unroll
    for (int u = 0; u < 2; ++u) {
        int idx = u * 512 + tid;
        if (idx < 8 * 127) {
            int h = idx / 127, d = idx - h * 127;
            BT[h * 128 + d] = biasT[idx];
        }
    }

    // ---- stage X once into fragment-linear LDS (conflict-free) ----
    {
        const float* xb = x + (size_t)blk * (LTOK * CDIM);
        #pragma unroll
        for (int q = 0; q < 4; ++q) {
            int f = q * 8 + w;                 // frag id: kt = f>>2, rt = f&3
            int kt = f >> 2, rt = f & 3;
            const float* src = xb + (size_t)(rt * 16 + lc) * CDIM + kt * 32 + lg * 8;
            f32x4 a = *(const f32x4*)(src);
            f32x4 b = *(const f32x4*)(src + 4);
            short8 t;
            t[0]=f2bf(a[0]); t[1]=f2bf(a[1]); t[2]=f2bf(a[2]); t[3]=f2bf(a[3]);
            t[4]=f2bf(b[0]); t[5]=f2bf(b[1]); t[6]=f2bf(b[2]); t[7]=f2bf(b[3]);
            *(short8*)(XSF + (size_t)(f * 64 + l) * 8) = t;
        }
    }

    f32x4 accP[4][2];                          // proj accumulators, persist
    #pragma unroll
    for (int a = 0; a < 4; ++a) { accP[a][0] = (f32x4){0,0,0,0}; accP[a][1] = (f32x4){0,0,0,0}; }
    const f32x4 fzero = {0.f, 0.f, 0.f, 0.f};

    const int mtb = (w >> 2) * 2;              // qkv m-tile base
    const int sb  = (w & 3) * 3;               // qkv strip base
    const int hh  = w >> 2;                    // attention: head within pair
    const int mw  = w & 3;                     // attention: q m-tile
    short* PW = PBF + w * 1024;                // wave-private P slice

    __syncthreads();                           // B0: XSF + BT ready

    #pragma unroll 1
    for (int g = 0; g < 4; ++g) {
        // ======== qkv GEMM: 3 strips x 2 m-tiles per wave ========
        f32x4 acc[3][2];
        #pragma unroll
        for (int t = 0; t < 3; ++t) { acc[t][0] = fzero; acc[t][1] = fzero; }
        #pragma unroll
        for (int kt = 0; kt < 8; ++kt) {
            short8 Af0 = *(const short8*)(XSF + (size_t)((kt * 4 + mtb) * 64 + l) * 8);
            short8 Af1 = *(const short8*)(XSF + (size_t)((kt * 4 + mtb + 1) * 64 + l) * 8);
            #pragma unroll
            for (int tt = 0; tt < 3; ++tt) {
                const int strip = sb + tt;
                const int gnt = (strip >> 2) * 16 + g * 4 + (strip & 3);
                short8 Bf = *(const short8*)(wqs + (size_t)((gnt * 8 + kt) * 64 + l) * 8);
                acc[tt][0] = __builtin_amdgcn_mfma_f32_16x16x32_bf16(Af0, Bf, acc[tt][0], 0, 0, 0);
                acc[tt][1] = __builtin_amdgcn_mfma_f32_16x16x32_bf16(Af1, Bf, acc[tt][1], 0, 0, 0);
            }
        }
        // ---- epilogue: scatter into fragment-linear QGF/KGF/VTF + NSQ ----
        #pragma unroll
        for (int tt = 0; tt < 3; ++tt) {
            const int strip = sb + tt;
            const int s = strip >> 2, nt = strip & 3;
            const float bq = qkv_b[s * 256 + g * 64 + nt * 16 + lc];
            #pragma unroll
            for (int m = 0; m < 2; ++m) {
                const int mt = mtb + m;
                if (s == 2) {
                    // V transposed: row=d (rt=nt), k=token
                    #pragma unroll
                    for (int i = 0; i < 4; ++i) {
                        int tok = li4 + i;     // token low bits (mt gives high)
                        VTF[(size_t)(((mt >> 1) * 4 + nt) * 64 + ((mt & 1) * 2 + (tok >> 3)) * 16 + lc) * 8 + (tok & 7)]
                            = f2bf(acc[tt][m][i] + bq);
                    }
                } else {
                    short* dst = s ? KGF : U;
                    const int ktc = nt >> 1;
                    const int lgc = (nt & 1) * 2 + (lc >> 3);
                    #pragma unroll
                    for (int i = 0; i < 4; ++i) {
                        float v = acc[tt][m][i] + bq;
                        dst[(size_t)((ktc * 4 + mt) * 64 + lgc * 16 + li4 + i) * 8 + (lc & 7)] = f2bf(v);
                        float t2 = v * v;
                        t2 += __shfl_xor(t2, 1);
                        t2 += __shfl_xor(t2, 2);
                        t2 += __shfl_xor(t2, 4);
                        t2 += __shfl_xor(t2, 8);
                        if (lc == 0) NSQ[s * 256 + (mt * 16 + li4 + i) * 4 + nt] = t2;
                    }
                }
            }
        }
        __syncthreads();                       // B1: QGF/KGF/VTF/NSQ ready

        // ======== attention (both heads concurrent across wave groups) ========
        {
            const int h = 2 * g + hh;
            const float sc = scT[h];
            short8 Aq = *(const short8*)(U + (size_t)((hh * 4 + mw) * 64 + l) * 8);
            f32x4 pacc[4];
            #pragma unroll
            for (int nt = 0; nt < 4; ++nt) {
                short8 Bk = *(const short8*)(KGF + (size_t)((hh * 4 + nt) * 64 + l) * 8);
                pacc[nt] = __builtin_amdgcn_mfma_f32_16x16x32_bf16(Aq, Bk, fzero, 0, 0, 0);
            }
            float invq[4], invk[4];
            #pragma unroll
            for (int i = 0; i < 4; ++i) {
                int r = mw * 16 + li4 + i;
                invq[i] = rsqrtf(NSQ[r * 4 + 2 * hh] + NSQ[r * 4 + 2 * hh + 1] + 1e-24f) * sc;
            }
            #pragma unroll
            for (int nt = 0; nt < 4; ++nt) {
                int rk = nt * 16 + lc;
                invk[nt] = rsqrtf(NSQ[256 + rk * 4 + 2 * hh] + NSQ[256 + rk * 4 + 2 * hh + 1] + 1e-24f);
            }
            float p[4][4];
            #pragma unroll
            for (int i = 0; i < 4; ++i) {
                int r = mw * 16 + li4 + i;
                #pragma unroll
                for (int nt = 0; nt < 4; ++nt)
                    p[i][nt] = pacc[nt][i] * invq[i] * invk[nt] + BT[h * 128 + r - (nt * 16 + lc) + 63];
            }
            // softmax over row (16-lane groups x 4 local)
            #pragma unroll
            for (int i = 0; i < 4; ++i) {
                float m = fmaxf(fmaxf(p[i][0], p[i][1]), fmaxf(p[i][2], p[i][3]));
                m = fmaxf(m, __shfl_xor(m, 1));
                m = fmaxf(m, __shfl_xor(m, 2));
                m = fmaxf(m, __shfl_xor(m, 4));
                m = fmaxf(m, __shfl_xor(m, 8));
                float ssum = 0.f;
                #pragma unroll
                for (int nt = 0; nt < 4; ++nt) { p[i][nt] = __expf(p[i][nt] - m); ssum += p[i][nt]; }
                ssum += __shfl_xor(ssum, 1);
                ssum += __shfl_xor(ssum, 2);
                ssum += __shfl_xor(ssum, 4);
                ssum += __shfl_xor(ssum, 8);
                float rinv = 1.f / ssum;
                #pragma unroll
                for (int nt = 0; nt < 4; ++nt) {
                    // wave-private P in A-frag layout (kt = nt>>1)
                    PW[(size_t)((nt >> 1) * 64 + ((nt & 1) * 2 + (lc >> 3)) * 16 + li4 + i) * 8 + (lc & 7)]
                        = f2bf(p[i][nt] * rinv);
                }
            }
            // ---- P @ V (wave-private P: no barrier, lgkmcnt only) ----
            f32x4 oacc[2];
            oacc[0] = fzero; oacc[1] = fzero;
            #pragma unroll
            for (int kt = 0; kt < 2; ++kt) {
                short8 Ap = *(const short8*)(PW + (size_t)(kt * 64 + l) * 8);
                #pragma unroll
                for (int nt2 = 0; nt2 < 2; ++nt2) {
                    short8 Bv = *(const short8*)(VTF + (size_t)((kt * 4 + hh * 2 + nt2) * 64 + l) * 8);
                    oacc[nt2] = __builtin_amdgcn_mfma_f32_16x16x32_bf16(Ap, Bv, oacc[nt2], 0, 0, 0);
                }
            }
            // AO into U slot (hh,mw) — same slot this wave read as Aq
            #pragma unroll
            for (int nt2 = 0; nt2 < 2; ++nt2)
                #pragma unroll
                for (int i = 0; i < 4; ++i)
                    U[(size_t)((hh * 4 + mw) * 64 + (nt2 * 2 + (lc >> 3)) * 16 + li4 + i) * 8 + (lc & 7)]
                        = f2bf(oacc[nt2][i]);
        }
        __syncthreads();                       // B2: AOF ready

        // ======== proj accumulate: wave w owns cols 32w..32w+31 ========
        #pragma unroll
        for (int hh2 = 0; hh2 < 2; ++hh2) {
            const int h2 = 2 * g + hh2;
            short8 Bp0 = *(const short8*)(wps + (size_t)(((w * 2 + 0) * 8 + h2) * 64 + l) * 8);
            short8 Bp1 = *(const short8*)(wps + (size_t)(((w * 2 + 1) * 8 + h2) * 64 + l) * 8);
            #pragma unroll
            for (int mt = 0; mt < 4; ++mt) {
                short8 Aa = *(const short8*)(U + (size_t)((hh2 * 4 + mt) * 64 + l) * 8);
                accP[mt][0] = __builtin_amdgcn_mfma_f32_16x16x32_bf16(Aa, Bp0, accP[mt][0], 0, 0, 0);
                accP[mt][1] = __builtin_amdgcn_mfma_f32_16x16x32_bf16(Aa, Bp1, accP[mt][1], 0, 0, 0);
            }
        }
        __syncthreads();                       // B3: proj done before next-g U/KGF/VTF/NSQ writes
    }

    // ---- epilogue: out = accP + proj_b ----
    {
        float* ob = out + (size_t)blk * (LTOK * CDIM);
        float pb0 = proj_b[w * 32 + lc];
        float pb1 = proj_b[w * 32 + 16 + lc];
        #pragma unroll
        for (int mt = 0; mt < 4; ++mt)
            #pragma unroll
            for (int i = 0; i < 4; ++i) {
                ob[(size_t)(mt * 16 + li4 + i) * 256 + w * 32 + lc]      = accP[mt][0][i] + pb0;
                ob[(size_t)(mt * 16 + li4 + i) * 256 + w * 32 + 16 + lc] = accP[mt][1][i] + pb1;
            }
    }
}

extern "C" void kernel_launch(void* const* d_in, const int* in_sizes, int n_in,
                              void* d_out, int out_size, void* d_ws, size_t ws_size,
                              hipStream_t stream) {
    const float* x     = (const float*)d_in[0];
    const float* qkvw  = (const float*)d_in[1];
    const float* qkvb  = (const float*)d_in[2];
    const float* projw = (const float*)d_in[3];
    const float* projb = (const float*)d_in[4];
    const float* lsc   = (const float*)d_in[5];
    const float* w1    = (const float*)d_in[6];
    const float* b1    = (const float*)d_in[7];
    const float* w2    = (const float*)d_in[8];
    const float* b2    = (const float*)d_in[9];
    float* out = (float*)d_out;

    // workspace layout
    short* wqs   = (short*)d_ws;                          // 393216 B
    short* wps   = (short*)((char*)d_ws + 393216);        // 131072 B
    float* biasT = (float*)((char*)d_ws + 524288);        // 4096 B
    float* scT   = (float*)((char*)d_ws + 528384);        // 32 B

    const int nwin = in_sizes[0] / (LTOK * CDIM);         // 4096

    prep_weights<<<768, 256, 0, stream>>>(qkvw, projw, wqs, wps);
    prep_bias<<<1, 128, 0, stream>>>(w1, b1, w2, b2, lsc, biasT, scT);
    fused_win_attn<<<nwin, 512, 0, stream>>>(x, qkvb, projb, wqs, wps, biasT, scT, out);
}